// Round 13
// baseline (178.339 us; speedup 1.0000x reference)
//
#include <hip/hip_runtime.h>
#include <hip/hip_bf16.h>

typedef __attribute__((ext_vector_type(8))) short short8;     // 8 bf16 (MFMA A/B frag, K=32)
typedef __attribute__((ext_vector_type(4))) float float4v;    // MFMA C/D frag

// RoPE on an 8-elem bf16 chunk (4 pairs). tA/tB = tab[p..p+1], tab[p+2..p+3]
// as (cos,sin,cos,sin). Identical rounding chain to the old qkv_prep path.
__device__ inline short8 rope8(short8 raw, float4 tA, float4 tB, float scale) {
  float c[4] = {tA.x, tA.z, tB.x, tB.z};
  float s[4] = {tA.y, tA.w, tB.y, tB.w};
  union { short8 v; short e[8]; } in, out;
  in.v = raw;
  #pragma unroll
  for (int j = 0; j < 4; ++j) {
    __hip_bfloat16 h1 = *reinterpret_cast<__hip_bfloat16*>(&in.e[2 * j]);
    __hip_bfloat16 h2 = *reinterpret_cast<__hip_bfloat16*>(&in.e[2 * j + 1]);
    const float x1 = __bfloat162float(h1), x2 = __bfloat162float(h2);
    __hip_bfloat16 o1 = __float2bfloat16((x1 * c[j] - x2 * s[j]) * scale);
    __hip_bfloat16 o2 = __float2bfloat16((x1 * s[j] + x2 * c[j]) * scale);
    out.e[2 * j]     = *reinterpret_cast<short*>(&o1);
    out.e[2 * j + 1] = *reinterpret_cast<short*>(&o2);
  }
  return out.v;
}

// ---------------------------------------------------------------------------
// prep_all: r25 exact form (r27's float4-load variant reverted — within
// noise, r25 is the known-good 170.2us draw).
// ---------------------------------------------------------------------------
__global__ __launch_bounds__(256) void prep_all(
    const float* __restrict__ x, __hip_bfloat16* __restrict__ xb,
    float2* __restrict__ tab,
    const float* __restrict__ Wqkv, const float* __restrict__ Wout,
    __hip_bfloat16* __restrict__ WqkvT, __hip_bfloat16* __restrict__ WoutT) {
  __shared__ __hip_bfloat16 tile[32][33];
  const int id = blockIdx.x;
  if (id < 4096) {
    const int i = id * 256 + threadIdx.x;
    const float4 v = *(const float4*)(x + (size_t)i * 4);
    __hip_bfloat16 o[4];
    o[0] = __float2bfloat16(v.x); o[1] = __float2bfloat16(v.y);
    o[2] = __float2bfloat16(v.z); o[3] = __float2bfloat16(v.w);
    *(uint2*)(xb + (size_t)i * 4) = *(const uint2*)o;
    return;
  }
  if (id < 4352) {
    const int i = (id - 4096) * 256 + threadIdx.x;   // 65536
    const int s = i >> 5, p = i & 31;
    const float freq = powf(10000.f, -(float)(p * 2) / 64.f);
    float sn, cs;
    sincosf((float)s * freq, &sn, &cs);
    tab[i] = make_float2(cs, sn);
    return;
  }
  const float* in;
  __hip_bfloat16* out;
  int C, bx, by;
  if (id < 7424) {
    const int lid = id - 4352;
    in = Wqkv; out = WqkvT; C = 3072; bx = lid % 96; by = lid / 96;
  } else {
    const int lid = id - 7424;
    in = Wout; out = WoutT; C = 1024; bx = lid & 31; by = lid >> 5;
  }
  const int R = 1024;
  const int c0 = bx * 32, r0 = by * 32;
  const int tx = threadIdx.x & 31, ty = threadIdx.x >> 5;  // ty 0..7
  #pragma unroll
  for (int i = ty; i < 32; i += 8)
    tile[i][tx] = __float2bfloat16(in[(size_t)(r0 + i) * C + (c0 + tx)]);
  __syncthreads();
  const int sx = threadIdx.x & 15, sy = threadIdx.x >> 4;  // sy 0..15
  #pragma unroll
  for (int i = sy; i < 32; i += 16) {
    union { unsigned u; short e[2]; } pk;
    pk.e[0] = *reinterpret_cast<short*>(&tile[2 * sx][i]);
    pk.e[1] = *reinterpret_cast<short*>(&tile[2 * sx + 1][i]);
    *(unsigned*)&out[(size_t)(c0 + i) * R + r0 + 2 * sx] = pk.u;
  }
}

// ---------------------------------------------------------------------------
// gemm_bt: r6/r12 measured-optimum 2-barrier structure. gemm1 pipelining
// CLOSED (r22 46us, r26 60us vs 40us here — 256^2 tiles give 192 blocks at
// 1 block/CU: barrier convoy with nothing to fill it).
// ---------------------------------------------------------------------------
template <typename OutT, int BM, int BN>
__global__ __launch_bounds__(256) void gemm_bt(
    const __hip_bfloat16* __restrict__ A,
    const __hip_bfloat16* __restrict__ Bt,
    OutT* __restrict__ C,
    int M, int N, int K) {
  __shared__ __hip_bfloat16 lA[BM][64];
  __shared__ __hip_bfloat16 lB[BN][64];
  constexpr int NI = BM / 32, NJ = BN / 32;
  const int t = threadIdx.x;
  const int lane = t & 63, wave = t >> 6;
  const int quad = lane >> 4, ln = lane & 15;
  const int m0 = blockIdx.y * BM, n0 = blockIdx.x * BN;
  const int wm = (wave >> 1) * (BM / 2), wn = (wave & 1) * (BN / 2);
  const int srow = lane >> 3;
  const int schunk = ((lane & 7) ^ srow) * 8;

  float4v acc[NI][NJ];
  #pragma unroll
  for (int i = 0; i < NI; ++i)
    #pragma unroll
    for (int j = 0; j < NJ; ++j)
      acc[i][j] = (float4v){0.f, 0.f, 0.f, 0.f};

  for (int kt = 0; kt < K; kt += 64) {
    __syncthreads();
    #pragma unroll
    for (int g = 0; g < BM / 32; ++g) {
      const int rbase = wave * (BM / 4) + g * 8;
      __builtin_amdgcn_global_load_lds(
          (const __attribute__((address_space(1))) void*)
              (A + (size_t)(m0 + rbase + srow) * K + kt + schunk),
          (__attribute__((address_space(3))) void*)&lA[rbase][0], 16, 0, 0);
    }
    #pragma unroll
    for (int g = 0; g < BN / 32; ++g) {
      const int rbase = wave * (BN / 4) + g * 8;
      __builtin_amdgcn_global_load_lds(
          (const __attribute__((address_space(1))) void*)
              (Bt + (size_t)(n0 + rbase + srow) * K + kt + schunk),
          (__attribute__((address_space(3))) void*)&lB[rbase][0], 16, 0, 0);
    }
    __syncthreads();
    #pragma unroll
    for (int step = 0; step < 2; ++step) {
      short8 af[NI], bf[NJ];
      #pragma unroll
      for (int i = 0; i < NI; ++i)
        af[i] = *(const short8*)&lA[wm + i * 16 + ln][((step * 4 + quad) ^ (ln & 7)) * 8];
      #pragma unroll
      for (int j = 0; j < NJ; ++j)
        bf[j] = *(const short8*)&lB[wn + j * 16 + ln][((step * 4 + quad) ^ (ln & 7)) * 8];
      #pragma unroll
      for (int i = 0; i < NI; ++i)
        #pragma unroll
        for (int j = 0; j < NJ; ++j)
          acc[i][j] = __builtin_amdgcn_mfma_f32_16x16x32_bf16(af[i], bf[j], acc[i][j], 0, 0, 0);
    }
  }
  #pragma unroll
  for (int i = 0; i < NI; ++i)
    #pragma unroll
    for (int j = 0; j < NJ; ++j)
      #pragma unroll
      for (int r = 0; r < 4; ++r) {
        const int row = m0 + wm + i * 16 + quad * 4 + r;
        const int col = n0 + wn + j * 16 + ln;
        if constexpr (__is_same(OutT, float))
          C[(size_t)row * N + col] = acc[i][j][r];
        else
          C[(size_t)row * N + col] = __float2bfloat16(acc[i][j][r]);
      }
}

// ---------------------------------------------------------------------------
// qkv_prep r25: K RoPE (vectorized 16B) + V transpose (8B both sides).
// ---------------------------------------------------------------------------
__global__ __launch_bounds__(256) void qkv_prep(
    const __hip_bfloat16* __restrict__ qkv,
    const float2* __restrict__ tab,
    __hip_bfloat16* __restrict__ K,
    __hip_bfloat16* __restrict__ Vt) {
  __shared__ __hip_bfloat16 tile[64][68];     // +4 pad: 8B-aligned rows
  const int s0 = blockIdx.x * 64;
  const int bh = blockIdx.y;
  const int h = bh & 15, b = bh >> 4;
  const int t = threadIdx.x;

  const int dd = (t & 7) * 8;
  const int sl = t >> 3;                      // 0..31
  #pragma unroll
  for (int ss = sl; ss < 64; ss += 32) {
    const int s = s0 + ss;
    short8 kv = *(const short8*)&qkv[(size_t)(b * 2048 + s) * 3072 + 1024 + h * 64 + dd];
    const float4 tA = *(const float4*)&tab[(size_t)s * 32 + (dd >> 1)];
    const float4 tB = *(const float4*)&tab[(size_t)s * 32 + (dd >> 1) + 2];
    *(short8*)&K[((size_t)bh * 2048 + s) * 64 + dd] = rope8(kv, tA, tB, 1.0f);
  }

  const int dgrp = (t & 15) * 4;              // d base for load
  const int srow = t >> 4;                    // 0..15
  #pragma unroll
  for (int i = srow; i < 64; i += 16) {
    ushort4 v4 = *(const ushort4*)&qkv[(size_t)(b * 2048 + s0 + i) * 3072 + 2048 + h * 64 + dgrp];
    *(ushort4*)&tile[i][dgrp] = v4;
  }
  __syncthreads();
  const int vx = t & 15, vy = t >> 4;         // vx -> s-quad, vy -> d
  #pragma unroll
  for (int d = vy; d < 64; d += 16) {
    union { ushort4 v; short e[4]; } pk;
    #pragma unroll
    for (int jj = 0; jj < 4; ++jj)
      pk.e[jj] = *reinterpret_cast<short*>(&tile[4 * vx + jj][d]);
    *(ushort4*)&Vt[((size_t)bh * 64 + d) * 2048 + s0 + 4 * vx] = pk.v;
  }
}

// ---------------------------------------------------------------------------
// Flash-style causal attention — r28: SPLIT-KV for long q-tiles.
// Attention is chain-bound (r3/r4: wall = longest block's 32-iter serial
// chain, all pipes <30%). q-tiles 16..31 split into two KV-halves run as
// independent blocks (A=[0,hA), B=[hA,qt]), each writing UNNORMALIZED fp32
// partial O (layout [half][bh][qrel][d]) + partial l; attn_combine sums and
// normalizes. q-tiles 0..15 (chain already <=16) keep the exact r25 path.
// Max chain 32 -> 16. Per-iter structure (swapped-operand QK, in-register P,
// f-swizzle lK, fused RoPE-Q) UNCHANGED; only loop bounds + epilogue branch.
// Masking kt==qt reachable only in the block owning the diagonal (unsplit,
// or split-B whose hi-1==qt; split-A hi-1 <= 15 < qt).
// Grid 1536 = 32bh x {16 unsplit r<16, 16 split-A r in 16..31, 16 split-B}.
// ---------------------------------------------------------------------------
__global__ __launch_bounds__(256) void attention(
    const __hip_bfloat16* __restrict__ qkv,
    const float2* __restrict__ tab,
    const __hip_bfloat16* __restrict__ K,
    const __hip_bfloat16* __restrict__ Vt,
    __hip_bfloat16* __restrict__ attn,
    float* __restrict__ Op,               // 2 x 32 x 1024 x 64 fp32
    float* __restrict__ lp) {             // 2 x 32 x 1024 fp32
  __shared__ __hip_bfloat16 lK[2][64][64];    // [buf][sk][d]  f-swizzled, dbuf
  __shared__ __hip_bfloat16 lV[2][64][64];    // [buf][d][sk]  XOR-swizzled, dbuf
  __shared__ __hip_bfloat16 lO[4][16][64];    // per-wave epilogue transpose
  const int t = threadIdx.x;
  const int lane = t & 63, w = t >> 6;
  const int quad = lane >> 4, ln = lane & 15;
  const int id = blockIdx.x;
  const int bh = id & 31;                     // fast index -> XCD spread
  const int r = id >> 5;                      // 0..47
  int qt, lo, hi, half;
  bool split;
  if (r < 16)      { split = false; half = 0; qt = r;      lo = 0;             hi = qt + 1; }
  else if (r < 32) { split = true;  half = 0; qt = r;      lo = 0;             hi = (qt + 2) >> 1; }
  else             { split = true;  half = 1; qt = r - 16; lo = (qt + 2) >> 1; hi = qt + 1; }
  const int q0 = qt * 64;
  const size_t base = (size_t)bh * 2048 * 64;
  const __hip_bfloat16* Kb = K + base;
  const __hip_bfloat16* Vb = Vt + base;
  const int b = bh >> 4, h = bh & 15;

  const int srow = lane >> 3;
  const int schunkV = ((lane & 7) ^ srow) * 8;            // V: f(r) = r&7
  const int rb0 = w * 16;
  const int sig_base = (ln >> 2) * 8 + (ln & 3);

  // Prologue: stage tile `lo` into buf 0.
  #pragma unroll
  for (int g2 = 0; g2 < 2; ++g2) {
    const int rbase = rb0 + g2 * 8;
    const int schunkK = (((lane & 7) ^ srow) ^ (g2 << 2)) * 8;  // f-bit2 = g2
    __builtin_amdgcn_global_load_lds(
        (const __attribute__((address_space(1))) void*)
            (Kb + (size_t)(lo * 64 + rbase + srow) * 64 + schunkK),
        (__attribute__((address_space(3))) void*)&lK[0][rbase][0], 16, 0, 0);
    __builtin_amdgcn_global_load_lds(
        (const __attribute__((address_space(1))) void*)
            (Vb + (size_t)(rbase + srow) * 2048 + lo * 64 + schunkV),
        (__attribute__((address_space(3))) void*)&lV[0][rbase][0], 16, 0, 0);
  }

  // qf: raw qkv q-slice + fused RoPE (scale = (1/8)*log2(e) for exp2-softmax)
  short8 qf[2];
  {
    const float qs = 0.125f * 1.44269504088896340736f;
    const int s = q0 + w * 16 + ln;
    const size_t qrow = (size_t)(b * 2048 + s) * 3072 + h * 64;
    short8 raw0 = *(const short8*)&qkv[qrow + quad * 8];
    short8 raw1 = *(const short8*)&qkv[qrow + 32 + quad * 8];
    const float4 ta = *(const float4*)&tab[(size_t)s * 32 + quad * 4];
    const float4 tb = *(const float4*)&tab[(size_t)s * 32 + quad * 4 + 2];
    const float4 tc = *(const float4*)&tab[(size_t)s * 32 + 16 + quad * 4];
    const float4 td = *(const float4*)&tab[(size_t)s * 32 + 16 + quad * 4 + 2];
    qf[0] = rope8(raw0, ta, tb, qs);
    qf[1] = rope8(raw1, tc, td, qs);
  }

  float4v acc_o[4];
  #pragma unroll
  for (int dt = 0; dt < 4; ++dt) acc_o[dt] = (float4v){0.f, 0.f, 0.f, 0.f};
  float suml = 0.f;

  for (int kt = lo; kt < hi; ++kt) {
    const int buf = (kt - lo) & 1;
    __syncthreads();   // drains tile-kt DMA (issued a full iter ago)

    if (kt + 1 < hi) {
      #pragma unroll
      for (int g2 = 0; g2 < 2; ++g2) {
        const int rbase = rb0 + g2 * 8;
        const int schunkK = (((lane & 7) ^ srow) ^ (g2 << 2)) * 8;
        __builtin_amdgcn_global_load_lds(
            (const __attribute__((address_space(1))) void*)
                (Kb + (size_t)((kt + 1) * 64 + rbase + srow) * 64 + schunkK),
            (__attribute__((address_space(3))) void*)&lK[buf ^ 1][rbase][0], 16, 0, 0);
        __builtin_amdgcn_global_load_lds(
            (const __attribute__((address_space(1))) void*)
                (Vb + (size_t)(rbase + srow) * 2048 + (kt + 1) * 64 + schunkV),
            (__attribute__((address_space(3))) void*)&lV[buf ^ 1][rbase][0], 16, 0, 0);
      }
    }

    // QK^T swapped: s4[nt] lane(quad,ln) reg r = P[sigma(nt,quad*4+r)][q=ln]
    float4v s4[4];
    #pragma unroll
    for (int nt = 0; nt < 4; ++nt) {
      const int krow = sig_base + ((nt & 1) << 2) + ((nt >> 1) << 5);
      const int k7 = (krow & 7) ^ (((krow >> 3) & 1) << 2);   // f(krow)
      float4v a = (float4v){0.f, 0.f, 0.f, 0.f};
      #pragma unroll
      for (int step = 0; step < 2; ++step) {
        short8 kf = *(const short8*)&lK[buf][krow][((step * 4 + quad) ^ k7) * 8];
        a = __builtin_amdgcn_mfma_f32_16x16x32_bf16(kf, qf[step], a, 0, 0, 0);
      }
      s4[nt] = a;
    }
    if (kt == qt) {
      const int qr = q0 + w * 16 + ln;
      #pragma unroll
      for (int nt = 0; nt < 4; ++nt)
        #pragma unroll
        for (int rr = 0; rr < 4; ++rr) {
          const int kglob = kt * 64 + quad * 8 + ((nt & 1) << 2) + rr + ((nt >> 1) << 5);
          if (kglob > qr) s4[nt][rr] = -64.f;
        }
    }
    #pragma unroll
    for (int nt = 0; nt < 4; ++nt)
      #pragma unroll
      for (int rr = 0; rr < 4; ++rr) {
        s4[nt][rr] = __builtin_amdgcn_exp2f(s4[nt][rr]);
        suml += s4[nt][rr];
      }
    #pragma unroll
    for (int s = 0; s < 2; ++s) {
      union { short8 v; short e[8]; } pb;
      #pragma unroll
      for (int i = 0; i < 4; ++i) {
        __hip_bfloat16 b0 = __float2bfloat16(s4[2 * s][i]);
        __hip_bfloat16 b1 = __float2bfloat16(s4[2 * s + 1][i]);
        pb.e[i] = *reinterpret_cast<short*>(&b0);
        pb.e[4 + i] = *reinterpret_cast<short*>(&b1);
      }
      #pragma unroll
      for (int dt = 0; dt < 4; ++dt) {
        short8 vf = *(const short8*)&lV[buf][dt * 16 + ln][((s * 4 + quad) ^ (ln & 7)) * 8];
        acc_o[dt] = __builtin_amdgcn_mfma_f32_16x16x32_bf16(vf, pb.v, acc_o[dt], 0, 0, 0);
      }
    }
  }

  // l[q] = sum over the 4 quads holding q=ln's P-columns
  float l0 = suml + __shfl_xor(suml, 16);
  const float lfull = l0 + __shfl_xor(l0, 32);

  if (!split) {
    const float inv = 1.0f / lfull;
    #pragma unroll
    for (int dt = 0; dt < 4; ++dt) {
      union { uint2 u; short e[4]; } pk;
      #pragma unroll
      for (int rr = 0; rr < 4; ++rr) {
        __hip_bfloat16 bv = __float2bfloat16(acc_o[dt][rr] * inv);
        pk.e[rr] = *reinterpret_cast<short*>(&bv);
      }
      *(uint2*)&lO[w][ln][dt * 16 + quad * 4] = pk.u;
    }
    const int orow = lane >> 2;           // q' 0..15
    const int od = (lane & 3) * 16;       // d base (16 elems = 32B per lane)
    const uint4 w0 = *(const uint4*)&lO[w][orow][od];
    const uint4 w1 = *(const uint4*)&lO[w][orow][od + 8];
    const size_t rg = (size_t)(b * 2048 + q0 + w * 16 + orow);
    *(uint4*)&attn[rg * 1024 + h * 64 + od] = w0;
    *(uint4*)&attn[rg * 1024 + h * 64 + od + 8] = w1;
  } else {
    // partial store: qrel in [0,1024) over q-tiles 16..31
    const int qrel = (qt - 16) * 64 + w * 16 + ln;
    const size_t rowoff = ((size_t)half * 32 + bh) * 1024 + qrel;
    if (quad == 0) lp[rowoff] = lfull;
    float* Ob = Op + rowoff * 64;
    #pragma unroll
    for (int dt = 0; dt < 4; ++dt)
      *(float4v*)&Ob[dt * 16 + quad * 4] = acc_o[dt];
  }
}

// ---------------------------------------------------------------------------
// attn_combine (r28): out = (O_A + O_B) / (l_A + l_B) for q-tiles 16..31.
// 2048 blocks x 256 thr, 4 d per thread (16B fp32 reads, 8B bf16 write).
// ---------------------------------------------------------------------------
__global__ __launch_bounds__(256) void attn_combine(
    const float* __restrict__ Op, const float* __restrict__ lp,
    __hip_bfloat16* __restrict__ attn) {
  const int i = blockIdx.x * 256 + threadIdx.x;   // 0..524287
  const int d4 = (i & 15) * 4;
  const int srel = (i >> 4) & 1023;
  const int bh = i >> 14;                          // 0..31
  const size_t rowoff = (size_t)bh * 1024 + srel;
  const float l = lp[rowoff] + lp[(size_t)32 * 1024 + rowoff];
  const float inv = 1.0f / l;
  const float4 o0 = *(const float4*)&Op[rowoff * 64 + d4];
  const float4 o1 = *(const float4*)&Op[(size_t)32 * 1024 * 64 + rowoff * 64 + d4];
  const int b = bh >> 4, h = bh & 15, s = 1024 + srel;
  __hip_bfloat16 o[4];
  o[0] = __float2bfloat16((o0.x + o1.x) * inv);
  o[1] = __float2bfloat16((o0.y + o1.y) * inv);
  o[2] = __float2bfloat16((o0.z + o1.z) * inv);
  o[3] = __float2bfloat16((o0.w + o1.w) * inv);
  *(uint2*)&attn[((size_t)(b * 2048 + s)) * 1024 + h * 64 + d4] = *(const uint2*)o;
}

// ---------------------------------------------------------------------------
extern "C" void kernel_launch(void* const* d_in, const int* in_sizes, int n_in,
                              void* d_out, int out_size, void* d_ws, size_t ws_size,
                              hipStream_t stream) {
  const float* x    = (const float*)d_in[0];  // (2,2048,1024) fp32
  const float* Wqkv = (const float*)d_in[1];  // (1024,3072)   fp32
  const float* Wout = (const float*)d_in[2];  // (1024,1024)   fp32
  float* out = (float*)d_out;                 // (2,2048,1024) fp32

  __hip_bfloat16* ws = (__hip_bfloat16*)d_ws;
  __hip_bfloat16* xb    = ws;                          // 4096*1024
  __hip_bfloat16* WqkvT = xb    + (size_t)4096 * 1024; // 3072*1024
  __hip_bfloat16* WoutT = WqkvT + (size_t)3072 * 1024; // 1024*1024
  __hip_bfloat16* qkv   = WoutT + (size_t)1024 * 1024; // 4096*3072
  __hip_bfloat16* Q     = qkv   + (size_t)4096 * 3072; // slot unused (r25)
  __hip_bfloat16* K     = Q     + (size_t)32 * 2048 * 64;
  __hip_bfloat16* Vt    = K     + (size_t)32 * 2048 * 64;
  __hip_bfloat16* attn  = Vt    + (size_t)32 * 2048 * 64;  // dedicated
  float2*         tab   = (float2*)(attn + (size_t)4096 * 1024);  // 2048x32
  float*          Op    = (float*)(tab + (size_t)2048 * 32);      // 2x32x1024x64
  float*          lp    = Op + (size_t)2 * 32 * 1024 * 64;        // 2x32x1024

  prep_all<<<8448, 256, 0, stream>>>(x, xb, tab, Wqkv, Wout, WqkvT, WoutT);
  gemm_bt<__hip_bfloat16, 128, 128><<<dim3(3072 / 128, 4096 / 128), 256, 0, stream>>>(xb, WqkvT, qkv, 4096, 3072, 1024);
  qkv_prep<<<dim3(32, 32), 256, 0, stream>>>(qkv, tab, K, Vt);
  attention<<<1536, 256, 0, stream>>>(qkv, tab, K, Vt, attn, Op, lp);
  attn_combine<<<2048, 256, 0, stream>>>(Op, lp, attn);
  gemm_bt<float, 128, 64><<<dim3(1024 / 64, 4096 / 128), 256, 0, stream>>>(attn, WoutT, out, 4096, 1024, 1024);
}

// Round 14
// 174.541 us; speedup vs baseline: 1.0218x; 1.0218x over previous
//
#include <hip/hip_runtime.h>
#include <hip/hip_bf16.h>

typedef __attribute__((ext_vector_type(8))) short short8;     // 8 bf16 (MFMA A/B frag, K=32)
typedef __attribute__((ext_vector_type(4))) float float4v;    // MFMA C/D frag

// RoPE on an 8-elem bf16 chunk (4 pairs). tA/tB = tab[p..p+1], tab[p+2..p+3]
// as (cos,sin,cos,sin). Identical rounding chain to the old qkv_prep path.
__device__ inline short8 rope8(short8 raw, float4 tA, float4 tB, float scale) {
  float c[4] = {tA.x, tA.z, tB.x, tB.z};
  float s[4] = {tA.y, tA.w, tB.y, tB.w};
  union { short8 v; short e[8]; } in, out;
  in.v = raw;
  #pragma unroll
  for (int j = 0; j < 4; ++j) {
    __hip_bfloat16 h1 = *reinterpret_cast<__hip_bfloat16*>(&in.e[2 * j]);
    __hip_bfloat16 h2 = *reinterpret_cast<__hip_bfloat16*>(&in.e[2 * j + 1]);
    const float x1 = __bfloat162float(h1), x2 = __bfloat162float(h2);
    __hip_bfloat16 o1 = __float2bfloat16((x1 * c[j] - x2 * s[j]) * scale);
    __hip_bfloat16 o2 = __float2bfloat16((x1 * s[j] + x2 * c[j]) * scale);
    out.e[2 * j]     = *reinterpret_cast<short*>(&o1);
    out.e[2 * j + 1] = *reinterpret_cast<short*>(&o2);
  }
  return out.v;
}

// ---------------------------------------------------------------------------
// prep_all: all input prep in ONE launch (r25 form — measured best).
//   blocks [0,4096):     x fp32 -> xb bf16 (float4 vectorized)
//   blocks [4096,4352):  RoPE table tab[s][p] = (cos,sin), 512 KB, L2-resident
//   blocks [4352,7424):  Wqkv (1024x3072) -> WqkvT (3072x1024) bf16 transpose
//   blocks [7424,8448):  Wout (1024x1024) -> WootT transpose
// ---------------------------------------------------------------------------
__global__ __launch_bounds__(256) void prep_all(
    const float* __restrict__ x, __hip_bfloat16* __restrict__ xb,
    float2* __restrict__ tab,
    const float* __restrict__ Wqkv, const float* __restrict__ Wout,
    __hip_bfloat16* __restrict__ WqkvT, __hip_bfloat16* __restrict__ WoutT) {
  __shared__ __hip_bfloat16 tile[32][33];
  const int id = blockIdx.x;
  if (id < 4096) {
    const int i = id * 256 + threadIdx.x;
    const float4 v = *(const float4*)(x + (size_t)i * 4);
    __hip_bfloat16 o[4];
    o[0] = __float2bfloat16(v.x); o[1] = __float2bfloat16(v.y);
    o[2] = __float2bfloat16(v.z); o[3] = __float2bfloat16(v.w);
    *(uint2*)(xb + (size_t)i * 4) = *(const uint2*)o;
    return;
  }
  if (id < 4352) {
    const int i = (id - 4096) * 256 + threadIdx.x;   // 65536
    const int s = i >> 5, p = i & 31;
    const float freq = powf(10000.f, -(float)(p * 2) / 64.f);
    float sn, cs;
    sincosf((float)s * freq, &sn, &cs);
    tab[i] = make_float2(cs, sn);
    return;
  }
  const float* in;
  __hip_bfloat16* out;
  int C, bx, by;
  if (id < 7424) {
    const int lid = id - 4352;
    in = Wqkv; out = WqkvT; C = 3072; bx = lid % 96; by = lid / 96;
  } else {
    const int lid = id - 7424;
    in = Wout; out = WoutT; C = 1024; bx = lid & 31; by = lid >> 5;
  }
  const int R = 1024;
  const int c0 = bx * 32, r0 = by * 32;
  const int tx = threadIdx.x & 31, ty = threadIdx.x >> 5;  // ty 0..7
  #pragma unroll
  for (int i = ty; i < 32; i += 8)
    tile[i][tx] = __float2bfloat16(in[(size_t)(r0 + i) * C + (c0 + tx)]);
  __syncthreads();
  const int sx = threadIdx.x & 15, sy = threadIdx.x >> 4;  // sy 0..15
  #pragma unroll
  for (int i = sy; i < 32; i += 16) {
    union { unsigned u; short e[2]; } pk;
    pk.e[0] = *reinterpret_cast<short*>(&tile[2 * sx][i]);
    pk.e[1] = *reinterpret_cast<short*>(&tile[2 * sx + 1][i]);
    *(unsigned*)&out[(size_t)(c0 + i) * R + r0 + 2 * sx] = pk.u;
  }
}

// ---------------------------------------------------------------------------
// gemm_bt: C (MxN, OutT) = A (MxK, row-major bf16) @ Bt^T  (Bt is NxK bf16)
// r6/r12 measured-optimum 2-barrier structure. gemm1 pipelining CLOSED
// (r22 coarse ring 46us, r26 4-phase counted-vmcnt 60us vs 40us here —
// 256^2 tiles give 192 blocks at 1 block/CU: barrier convoy, nothing fills).
// Attention split-KV also CLOSED (r28: chain halving fully offset by +70%
// traffic; co-resident blocks already pipeline their chains).
// gemm1: <bf16,128,128> (768 blocks); gemm2: <float,128,64> (512 blocks).
// ---------------------------------------------------------------------------
template <typename OutT, int BM, int BN>
__global__ __launch_bounds__(256) void gemm_bt(
    const __hip_bfloat16* __restrict__ A,
    const __hip_bfloat16* __restrict__ Bt,
    OutT* __restrict__ C,
    int M, int N, int K) {
  __shared__ __hip_bfloat16 lA[BM][64];
  __shared__ __hip_bfloat16 lB[BN][64];
  constexpr int NI = BM / 32, NJ = BN / 32;
  const int t = threadIdx.x;
  const int lane = t & 63, wave = t >> 6;
  const int quad = lane >> 4, ln = lane & 15;
  const int m0 = blockIdx.y * BM, n0 = blockIdx.x * BN;
  const int wm = (wave >> 1) * (BM / 2), wn = (wave & 1) * (BN / 2);
  const int srow = lane >> 3;
  const int schunk = ((lane & 7) ^ srow) * 8;

  float4v acc[NI][NJ];
  #pragma unroll
  for (int i = 0; i < NI; ++i)
    #pragma unroll
    for (int j = 0; j < NJ; ++j)
      acc[i][j] = (float4v){0.f, 0.f, 0.f, 0.f};

  for (int kt = 0; kt < K; kt += 64) {
    __syncthreads();
    #pragma unroll
    for (int g = 0; g < BM / 32; ++g) {
      const int rbase = wave * (BM / 4) + g * 8;
      __builtin_amdgcn_global_load_lds(
          (const __attribute__((address_space(1))) void*)
              (A + (size_t)(m0 + rbase + srow) * K + kt + schunk),
          (__attribute__((address_space(3))) void*)&lA[rbase][0], 16, 0, 0);
    }
    #pragma unroll
    for (int g = 0; g < BN / 32; ++g) {
      const int rbase = wave * (BN / 4) + g * 8;
      __builtin_amdgcn_global_load_lds(
          (const __attribute__((address_space(1))) void*)
              (Bt + (size_t)(n0 + rbase + srow) * K + kt + schunk),
          (__attribute__((address_space(3))) void*)&lB[rbase][0], 16, 0, 0);
    }
    __syncthreads();
    #pragma unroll
    for (int step = 0; step < 2; ++step) {
      short8 af[NI], bf[NJ];
      #pragma unroll
      for (int i = 0; i < NI; ++i)
        af[i] = *(const short8*)&lA[wm + i * 16 + ln][((step * 4 + quad) ^ (ln & 7)) * 8];
      #pragma unroll
      for (int j = 0; j < NJ; ++j)
        bf[j] = *(const short8*)&lB[wn + j * 16 + ln][((step * 4 + quad) ^ (ln & 7)) * 8];
      #pragma unroll
      for (int i = 0; i < NI; ++i)
        #pragma unroll
        for (int j = 0; j < NJ; ++j)
          acc[i][j] = __builtin_amdgcn_mfma_f32_16x16x32_bf16(af[i], bf[j], acc[i][j], 0, 0, 0);
    }
  }
  #pragma unroll
  for (int i = 0; i < NI; ++i)
    #pragma unroll
    for (int j = 0; j < NJ; ++j)
      #pragma unroll
      for (int r = 0; r < 4; ++r) {
        const int row = m0 + wm + i * 16 + quad * 4 + r;
        const int col = n0 + wn + j * 16 + ln;
        if constexpr (__is_same(OutT, float))
          C[(size_t)row * N + col] = acc[i][j][r];
        else
          C[(size_t)row * N + col] = __float2bfloat16(acc[i][j][r]);
      }
}

// ---------------------------------------------------------------------------
// qkv_prep r25: K RoPE (vectorized 16B) + V transpose (8B both sides).
// Q dropped — attention fuses RoPE-Q into its one-time qf load.
// ---------------------------------------------------------------------------
__global__ __launch_bounds__(256) void qkv_prep(
    const __hip_bfloat16* __restrict__ qkv,
    const float2* __restrict__ tab,
    __hip_bfloat16* __restrict__ K,
    __hip_bfloat16* __restrict__ Vt) {
  __shared__ __hip_bfloat16 tile[64][68];     // +4 pad: 8B-aligned rows
  const int s0 = blockIdx.x * 64;
  const int bh = blockIdx.y;
  const int h = bh & 15, b = bh >> 4;
  const int t = threadIdx.x;

  const int dd = (t & 7) * 8;
  const int sl = t >> 3;                      // 0..31
  #pragma unroll
  for (int ss = sl; ss < 64; ss += 32) {
    const int s = s0 + ss;
    short8 kv = *(const short8*)&qkv[(size_t)(b * 2048 + s) * 3072 + 1024 + h * 64 + dd];
    const float4 tA = *(const float4*)&tab[(size_t)s * 32 + (dd >> 1)];
    const float4 tB = *(const float4*)&tab[(size_t)s * 32 + (dd >> 1) + 2];
    *(short8*)&K[((size_t)bh * 2048 + s) * 64 + dd] = rope8(kv, tA, tB, 1.0f);
  }

  const int dgrp = (t & 15) * 4;              // d base for load
  const int srow = t >> 4;                    // 0..15
  #pragma unroll
  for (int i = srow; i < 64; i += 16) {
    ushort4 v4 = *(const ushort4*)&qkv[(size_t)(b * 2048 + s0 + i) * 3072 + 2048 + h * 64 + dgrp];
    *(ushort4*)&tile[i][dgrp] = v4;
  }
  __syncthreads();
  const int vx = t & 15, vy = t >> 4;         // vx -> s-quad, vy -> d
  #pragma unroll
  for (int d = vy; d < 64; d += 16) {
    union { ushort4 v; short e[4]; } pk;
    #pragma unroll
    for (int jj = 0; jj < 4; ++jj)
      pk.e[jj] = *reinterpret_cast<short*>(&tile[4 * vx + jj][d]);
    *(ushort4*)&Vt[((size_t)bh * 64 + d) * 2048 + s0 + 4 * vx] = pk.v;
  }
}

// ---------------------------------------------------------------------------
// Flash-style causal attention — r25 form (measured best): swapped-operand
// QK (in-register P via sigma row perm), f-swizzle lK (bank-conflict fix),
// fused RoPE-Q, V dbuf, one barrier/iter, balanced qt perm, packed lO
// epilogue. QBLK=128 (r23), KVBLK=128 (r19), split-KV (r28) all falsified.
// ---------------------------------------------------------------------------
__global__ __launch_bounds__(256) void attention(
    const __hip_bfloat16* __restrict__ qkv,
    const float2* __restrict__ tab,
    const __hip_bfloat16* __restrict__ K,
    const __hip_bfloat16* __restrict__ Vt,
    __hip_bfloat16* __restrict__ attn) {
  __shared__ __hip_bfloat16 lK[2][64][64];    // [buf][sk][d]  f-swizzled, dbuf
  __shared__ __hip_bfloat16 lV[2][64][64];    // [buf][d][sk]  XOR-swizzled, dbuf
  __shared__ __hip_bfloat16 lO[4][16][64];    // per-wave epilogue transpose
  const int t = threadIdx.x;
  const int lane = t & 63, w = t >> 6;
  const int quad = lane >> 4, ln = lane & 15;
  const int id = blockIdx.x;
  const int bh = id & 31;                     // fast index -> XCD spread
  const int j = id >> 5;                      // 0..31
  const int k2 = j >> 3, g = j & 7;
  const int qt = 8 * k2 + ((k2 & 1) ? (7 - g) : g);   // balanced qt perm
  const int q0 = qt * 64;
  const size_t base = (size_t)bh * 2048 * 64;
  const __hip_bfloat16* Kb = K + base;
  const __hip_bfloat16* Vb = Vt + base;
  const int b = bh >> 4, h = bh & 15;

  const int srow = lane >> 3;
  const int schunkV = ((lane & 7) ^ srow) * 8;            // V: f(r) = r&7
  const int rb0 = w * 16;
  const int sig_base = (ln >> 2) * 8 + (ln & 3);

  #pragma unroll
  for (int g2 = 0; g2 < 2; ++g2) {
    const int rbase = rb0 + g2 * 8;
    const int schunkK = (((lane & 7) ^ srow) ^ (g2 << 2)) * 8;  // f-bit2 = g2
    __builtin_amdgcn_global_load_lds(
        (const __attribute__((address_space(1))) void*)
            (Kb + (size_t)(rbase + srow) * 64 + schunkK),
        (__attribute__((address_space(3))) void*)&lK[0][rbase][0], 16, 0, 0);
    __builtin_amdgcn_global_load_lds(
        (const __attribute__((address_space(1))) void*)
            (Vb + (size_t)(rbase + srow) * 2048 + schunkV),
        (__attribute__((address_space(3))) void*)&lV[0][rbase][0], 16, 0, 0);
  }

  // qf: raw qkv q-slice + fused RoPE (scale = (1/8)*log2(e) for exp2-softmax)
  short8 qf[2];
  {
    const float qs = 0.125f * 1.44269504088896340736f;
    const int s = q0 + w * 16 + ln;
    const size_t qrow = (size_t)(b * 2048 + s) * 3072 + h * 64;
    short8 raw0 = *(const short8*)&qkv[qrow + quad * 8];
    short8 raw1 = *(const short8*)&qkv[qrow + 32 + quad * 8];
    const float4 ta = *(const float4*)&tab[(size_t)s * 32 + quad * 4];
    const float4 tb = *(const float4*)&tab[(size_t)s * 32 + quad * 4 + 2];
    const float4 tc = *(const float4*)&tab[(size_t)s * 32 + 16 + quad * 4];
    const float4 td = *(const float4*)&tab[(size_t)s * 32 + 16 + quad * 4 + 2];
    qf[0] = rope8(raw0, ta, tb, qs);
    qf[1] = rope8(raw1, tc, td, qs);
  }

  float4v acc_o[4];
  #pragma unroll
  for (int dt = 0; dt < 4; ++dt) acc_o[dt] = (float4v){0.f, 0.f, 0.f, 0.f};
  float suml = 0.f;

  for (int kt = 0; kt <= qt; ++kt) {
    const int buf = kt & 1;
    __syncthreads();   // drains K[kt]/V[kt] DMA (issued a full iter ago);
                       // prev iter's buf^1 reads are all before this point

    if (kt < qt) {
      #pragma unroll
      for (int g2 = 0; g2 < 2; ++g2) {
        const int rbase = rb0 + g2 * 8;
        const int schunkK = (((lane & 7) ^ srow) ^ (g2 << 2)) * 8;
        __builtin_amdgcn_global_load_lds(
            (const __attribute__((address_space(1))) void*)
                (Kb + (size_t)((kt + 1) * 64 + rbase + srow) * 64 + schunkK),
            (__attribute__((address_space(3))) void*)&lK[buf ^ 1][rbase][0], 16, 0, 0);
        __builtin_amdgcn_global_load_lds(
            (const __attribute__((address_space(1))) void*)
                (Vb + (size_t)(rbase + srow) * 2048 + (kt + 1) * 64 + schunkV),
            (__attribute__((address_space(3))) void*)&lV[buf ^ 1][rbase][0], 16, 0, 0);
      }
    }

    // QK^T swapped: s4[nt] lane(quad,ln) reg r = P[sigma(nt,quad*4+r)][q=ln]
    float4v s4[4];
    #pragma unroll
    for (int nt = 0; nt < 4; ++nt) {
      const int krow = sig_base + ((nt & 1) << 2) + ((nt >> 1) << 5);
      const int k7 = (krow & 7) ^ (((krow >> 3) & 1) << 2);   // f(krow)
      float4v a = (float4v){0.f, 0.f, 0.f, 0.f};
      #pragma unroll
      for (int step = 0; step < 2; ++step) {
        short8 kf = *(const short8*)&lK[buf][krow][((step * 4 + quad) ^ k7) * 8];
        a = __builtin_amdgcn_mfma_f32_16x16x32_bf16(kf, qf[step], a, 0, 0, 0);
      }
      s4[nt] = a;
    }
    if (kt == qt) {
      const int qr = q0 + w * 16 + ln;
      #pragma unroll
      for (int nt = 0; nt < 4; ++nt)
        #pragma unroll
        for (int r = 0; r < 4; ++r) {
          const int kglob = kt * 64 + quad * 8 + ((nt & 1) << 2) + r + ((nt >> 1) << 5);
          if (kglob > qr) s4[nt][r] = -64.f;
        }
    }
    // exp (bare v_exp_f32) + row-sum contribution
    #pragma unroll
    for (int nt = 0; nt < 4; ++nt)
      #pragma unroll
      for (int r = 0; r < 4; ++r) {
        s4[nt][r] = __builtin_amdgcn_exp2f(s4[nt][r]);
        suml += s4[nt][r];
      }
    // PV: B-frag step s = lane-local pack of s4[2s][0..3], s4[2s+1][0..3]
    #pragma unroll
    for (int s = 0; s < 2; ++s) {
      union { short8 v; short e[8]; } pb;
      #pragma unroll
      for (int i = 0; i < 4; ++i) {
        __hip_bfloat16 b0 = __float2bfloat16(s4[2 * s][i]);
        __hip_bfloat16 b1 = __float2bfloat16(s4[2 * s + 1][i]);
        pb.e[i] = *reinterpret_cast<short*>(&b0);
        pb.e[4 + i] = *reinterpret_cast<short*>(&b1);
      }
      #pragma unroll
      for (int dt = 0; dt < 4; ++dt) {
        short8 vf = *(const short8*)&lV[buf][dt * 16 + ln][((s * 4 + quad) ^ (ln & 7)) * 8];
        acc_o[dt] = __builtin_amdgcn_mfma_f32_16x16x32_bf16(vf, pb.v, acc_o[dt], 0, 0, 0);
      }
    }
  }

  // l[q] = sum over the 4 quads holding q=ln's P-columns
  float l0 = suml + __shfl_xor(suml, 16);
  const float inv = 1.0f / (l0 + __shfl_xor(l0, 32));

  // Epilogue: lane holds O^T[d=dt*16+quad*4+r][q=ln]; transpose via per-wave
  // LDS tile; packed 8B writes (r-values contiguous in lO's col dim).
  #pragma unroll
  for (int dt = 0; dt < 4; ++dt) {
    union { uint2 u; short e[4]; } pk;
    #pragma unroll
    for (int r = 0; r < 4; ++r) {
      __hip_bfloat16 bv = __float2bfloat16(acc_o[dt][r] * inv);
      pk.e[r] = *reinterpret_cast<short*>(&bv);
    }
    *(uint2*)&lO[w][ln][dt * 16 + quad * 4] = pk.u;
  }

  const int orow = lane >> 2;           // q' 0..15
  const int od = (lane & 3) * 16;       // d base (16 elems = 32B per lane)
  const uint4 w0 = *(const uint4*)&lO[w][orow][od];
  const uint4 w1 = *(const uint4*)&lO[w][orow][od + 8];
  const size_t rg = (size_t)(b * 2048 + q0 + w * 16 + orow);
  *(uint4*)&attn[rg * 1024 + h * 64 + od] = w0;
  *(uint4*)&attn[rg * 1024 + h * 64 + od + 8] = w1;
}

// ---------------------------------------------------------------------------
extern "C" void kernel_launch(void* const* d_in, const int* in_sizes, int n_in,
                              void* d_out, int out_size, void* d_ws, size_t ws_size,
                              hipStream_t stream) {
  const float* x    = (const float*)d_in[0];  // (2,2048,1024) fp32
  const float* Wqkv = (const float*)d_in[1];  // (1024,3072)   fp32
  const float* Wout = (const float*)d_in[2];  // (1024,1024)   fp32
  float* out = (float*)d_out;                 // (2,2048,1024) fp32

  __hip_bfloat16* ws = (__hip_bfloat16*)d_ws;
  __hip_bfloat16* xb    = ws;                          // 4096*1024
  __hip_bfloat16* WqkvT = xb    + (size_t)4096 * 1024; // 3072*1024
  __hip_bfloat16* WoutT = WqkvT + (size_t)3072 * 1024; // 1024*1024
  __hip_bfloat16* qkv   = WoutT + (size_t)1024 * 1024; // 4096*3072
  __hip_bfloat16* Q     = qkv   + (size_t)4096 * 3072; // slot unused (r25)
  __hip_bfloat16* K     = Q     + (size_t)32 * 2048 * 64;
  __hip_bfloat16* Vt    = K     + (size_t)32 * 2048 * 64;
  __hip_bfloat16* attn  = Vt    + (size_t)32 * 2048 * 64;  // dedicated
  float2*         tab   = (float2*)(attn + (size_t)4096 * 1024);  // 2048x32

  prep_all<<<8448, 256, 0, stream>>>(x, xb, tab, Wqkv, Wout, WqkvT, WoutT);
  gemm_bt<__hip_bfloat16, 128, 128><<<dim3(3072 / 128, 4096 / 128), 256, 0, stream>>>(xb, WqkvT, qkv, 4096, 3072, 1024);
  qkv_prep<<<dim3(32, 32), 256, 0, stream>>>(qkv, tab, K, Vt);
  attention<<<1024, 256, 0, stream>>>(qkv, tab, K, Vt, attn);
  gemm_bt<float, 128, 64><<<dim3(1024 / 64, 4096 / 128), 256, 0, stream>>>(attn, WoutT, out, 4096, 1024, 1024);
}